// Round 1
// baseline (106.540 us; speedup 1.0000x reference)
//
#include <hip/hip_runtime.h>

// Problem constants (hard-coded to the reference shapes)
#define BQ 16
#define NP 4096
#define MP 4096

constexpr int TPB = 256;            // threads per block
constexpr int SRC_PER_THREAD = 4;   // src points per thread
constexpr int NCHUNK = TPB * SRC_PER_THREAD;  // 1024 src points per block
constexpr int MSPLIT = 8;           // split M across blocks for occupancy
constexpr int MSLICE = MP / MSPLIT; // 512 targets per block
constexpr int TILE = 256;           // targets per LDS tile (== TPB)

// ---------------------------------------------------------------------------
// Init: min-buffers to +inf, output scalar to 0 (harness poisons with 0xAA).
// ---------------------------------------------------------------------------
__global__ void chamfer_init_kernel(unsigned int* __restrict__ minbuf, int n,
                                    float* __restrict__ out) {
    int i = blockIdx.x * blockDim.x + threadIdx.x;
    if (i < n) minbuf[i] = 0x7F800000u;  // +inf bits
    if (i == 0) out[0] = 0.0f;
}

// ---------------------------------------------------------------------------
// Direction kernel. grid = (NP/NCHUNK, MSPLIT, 2*BQ).
//   blockIdx.z <  BQ : per-src-point min over targets (src -> tgt)
//   blockIdx.z >= BQ : roles swapped (tgt -> src)
// LDS tile holds targets pre-transformed to (-2x, -2y, -2z, t2) so the
// inner body is 3 fma + 1 min per pair; s2 is added after the min loop
// (min is monotone, so + s2 and the max(.,0) clamp commute with it).
// ---------------------------------------------------------------------------
__global__ __launch_bounds__(TPB) void chamfer_dir_kernel(
    const float* __restrict__ srcp,   // [BQ][NP][3]
    const float* __restrict__ tgtp,   // [BQ][MP][3]
    unsigned int* __restrict__ minbuf // [2][BQ][4096] float bits
) {
    const int bz  = blockIdx.z;
    const int dir = (bz >= BQ) ? 1 : 0;
    const int b   = dir ? (bz - BQ) : bz;

    const float* S = dir ? (tgtp + (size_t)b * MP * 3) : (srcp + (size_t)b * NP * 3);
    const float* T = dir ? (srcp + (size_t)b * NP * 3) : (tgtp + (size_t)b * MP * 3);
    unsigned int* outmin = minbuf + ((size_t)dir * BQ + b) * NP;

    __shared__ float4 tile[TILE];

    // Load this thread's source points (strided for coalescing across lanes).
    const int nbase = blockIdx.x * NCHUNK + threadIdx.x;
    float sx[SRC_PER_THREAD], sy[SRC_PER_THREAD], sz[SRC_PER_THREAD];
#pragma unroll
    for (int k = 0; k < SRC_PER_THREAD; ++k) {
        const float* p = S + (size_t)(nbase + k * TPB) * 3;
        sx[k] = p[0];
        sy[k] = p[1];
        sz[k] = p[2];
    }

    float mn[SRC_PER_THREAD];
#pragma unroll
    for (int k = 0; k < SRC_PER_THREAD; ++k) mn[k] = __int_as_float(0x7F800000);

    const int mbase = blockIdx.y * MSLICE;
    for (int m0 = 0; m0 < MSLICE; m0 += TILE) {
        // Stage one tile: each thread loads one target point.
        {
            const float* p = T + (size_t)(mbase + m0 + threadIdx.x) * 3;
            float tx = p[0], ty = p[1], tz = p[2];
            float t2 = fmaf(tx, tx, fmaf(ty, ty, tz * tz));
            tile[threadIdx.x] = make_float4(-2.0f * tx, -2.0f * ty, -2.0f * tz, t2);
        }
        __syncthreads();

#pragma unroll 4
        for (int j = 0; j < TILE; ++j) {
            float4 t = tile[j];  // broadcast read: conflict-free
#pragma unroll
            for (int k = 0; k < SRC_PER_THREAD; ++k) {
                float v = fmaf(sx[k], t.x, fmaf(sy[k], t.y, fmaf(sz[k], t.z, t.w)));
                mn[k] = fminf(mn[k], v);
            }
        }
        __syncthreads();
    }

    // Finalize: add s2, clamp at 0, merge across M-splits via uint atomicMin
    // (valid ordering since d2 >= 0).
#pragma unroll
    for (int k = 0; k < SRC_PER_THREAD; ++k) {
        float s2 = fmaf(sx[k], sx[k], fmaf(sy[k], sy[k], sz[k] * sz[k]));
        float d  = fmaxf(mn[k] + s2, 0.0f);
        atomicMin(&outmin[nbase + k * TPB], __float_as_uint(d));
    }
}

// ---------------------------------------------------------------------------
// Reduce: one block per batch. N == M == 4096, so
// mean_n(min) + mean_m(min) = (sum of both arrays) / 4096.
// ---------------------------------------------------------------------------
__global__ __launch_bounds__(TPB) void chamfer_reduce_kernel(
    const float* __restrict__ minbuf,   // [2][BQ][4096]
    const float* __restrict__ weights,  // [BQ]
    float* __restrict__ out) {
    const int b = blockIdx.x;
    const float* m0 = minbuf + (size_t)b * NP;
    const float* m1 = minbuf + ((size_t)BQ + b) * NP;

    float s = 0.0f;
    for (int i = threadIdx.x; i < NP; i += TPB) s += m0[i] + m1[i];

    // wave64 reduce
#pragma unroll
    for (int off = 32; off > 0; off >>= 1) s += __shfl_down(s, off, 64);

    __shared__ float red[TPB / 64];
    if ((threadIdx.x & 63) == 0) red[threadIdx.x >> 6] = s;
    __syncthreads();
    if (threadIdx.x == 0) {
        float tot = 0.0f;
#pragma unroll
        for (int w = 0; w < TPB / 64; ++w) tot += red[w];
        float val = weights[b] * (tot / (float)NP);  // mean1 + mean2 combined
        atomicAdd(out, val / (float)BQ);
    }
}

// ---------------------------------------------------------------------------
extern "C" void kernel_launch(void* const* d_in, const int* in_sizes, int n_in,
                              void* d_out, int out_size, void* d_ws, size_t ws_size,
                              hipStream_t stream) {
    const float* src = (const float*)d_in[0];
    const float* tgt = (const float*)d_in[1];
    const float* wts = (const float*)d_in[2];
    float* out = (float*)d_out;

    unsigned int* minbuf = (unsigned int*)d_ws;  // 2*BQ*NP floats = 512 KB
    const int minElems = 2 * BQ * NP;

    chamfer_init_kernel<<<(minElems + TPB - 1) / TPB, TPB, 0, stream>>>(
        minbuf, minElems, out);

    dim3 grid(NP / NCHUNK, MSPLIT, 2 * BQ);  // (4, 8, 32) = 1024 blocks
    chamfer_dir_kernel<<<grid, TPB, 0, stream>>>(src, tgt, minbuf);

    chamfer_reduce_kernel<<<BQ, TPB, 0, stream>>>((const float*)minbuf, wts, out);
}

// Round 2
// 105.325 us; speedup vs baseline: 1.0115x; 1.0115x over previous
//
#include <hip/hip_runtime.h>

// Problem constants (hard-coded to the reference shapes)
#define BQ 16
#define NP 4096
#define MP 4096

constexpr int TPB = 256;            // threads per block
constexpr int SRC_PER_THREAD = 8;   // src points per thread (amortize LDS broadcast)
constexpr int NCHUNK = TPB * SRC_PER_THREAD;  // 2048 src points per block
constexpr int MSPLIT = 16;          // split M across blocks for occupancy
constexpr int MSLICE = MP / MSPLIT; // 256 targets per block == one tile
constexpr int TILE = 256;           // targets per LDS tile (== TPB)

// ---------------------------------------------------------------------------
// Init: min-buffers to +inf, output scalar to 0 (harness poisons with 0xAA).
// ---------------------------------------------------------------------------
__global__ void chamfer_init_kernel(unsigned int* __restrict__ minbuf, int n,
                                    float* __restrict__ out) {
    int i = blockIdx.x * blockDim.x + threadIdx.x;
    if (i < n) minbuf[i] = 0x7F800000u;  // +inf bits
    if (i == 0) out[0] = 0.0f;
}

// ---------------------------------------------------------------------------
// Direction kernel. grid = (NP/NCHUNK, MSPLIT, 2*BQ) = (2, 16, 32).
//   blockIdx.z <  BQ : per-src-point min over targets (src -> tgt)
//   blockIdx.z >= BQ : roles swapped (tgt -> src)
// LDS tile holds targets pre-transformed to (-2x, -2y, -2z, t2) so the
// inner body is 3 fma per pair + shared v_min3 per pair of targets; s2 is
// added after the min loop (min is monotone; + s2 and max(.,0) commute).
// Each ds_read_b128 broadcast is amortized over 8 src points (the LDS
// return path at ~12cyc/b128 was co-dominant with VALU at SRC=4).
// ---------------------------------------------------------------------------
__global__ __launch_bounds__(TPB) void chamfer_dir_kernel(
    const float* __restrict__ srcp,   // [BQ][NP][3]
    const float* __restrict__ tgtp,   // [BQ][MP][3]
    unsigned int* __restrict__ minbuf // [2][BQ][4096] float bits
) {
    const int bz  = blockIdx.z;
    const int dir = (bz >= BQ) ? 1 : 0;
    const int b   = dir ? (bz - BQ) : bz;

    const float* S = dir ? (tgtp + (size_t)b * MP * 3) : (srcp + (size_t)b * NP * 3);
    const float* T = dir ? (srcp + (size_t)b * NP * 3) : (tgtp + (size_t)b * MP * 3);
    unsigned int* outmin = minbuf + ((size_t)dir * BQ + b) * NP;

    __shared__ float4 tile[TILE];

    // Stage the tile: each thread loads one target point.
    {
        const int m = blockIdx.y * MSLICE + threadIdx.x;
        const float* p = T + (size_t)m * 3;
        float tx = p[0], ty = p[1], tz = p[2];
        float t2 = fmaf(tx, tx, fmaf(ty, ty, tz * tz));
        tile[threadIdx.x] = make_float4(-2.0f * tx, -2.0f * ty, -2.0f * tz, t2);
    }

    // Load this thread's source points (strided for coalescing across lanes).
    const int nbase = blockIdx.x * NCHUNK + threadIdx.x;
    float sx[SRC_PER_THREAD], sy[SRC_PER_THREAD], sz[SRC_PER_THREAD];
#pragma unroll
    for (int k = 0; k < SRC_PER_THREAD; ++k) {
        const float* p = S + (size_t)(nbase + k * TPB) * 3;
        sx[k] = p[0];
        sy[k] = p[1];
        sz[k] = p[2];
    }

    float mn[SRC_PER_THREAD];
#pragma unroll
    for (int k = 0; k < SRC_PER_THREAD; ++k) mn[k] = __int_as_float(0x7F800000);

    __syncthreads();

#pragma unroll 2
    for (int j = 0; j < TILE; j += 2) {
        float4 ta = tile[j];      // broadcast reads: conflict-free
        float4 tb = tile[j + 1];
#pragma unroll
        for (int k = 0; k < SRC_PER_THREAD; ++k) {
            float v1 = fmaf(sx[k], ta.x, fmaf(sy[k], ta.y, fmaf(sz[k], ta.z, ta.w)));
            float v2 = fmaf(sx[k], tb.x, fmaf(sy[k], tb.y, fmaf(sz[k], tb.z, tb.w)));
            mn[k] = fminf(mn[k], fminf(v1, v2));  // -> v_min3_f32
        }
    }

    // Finalize: add s2, clamp at 0, merge across M-splits via uint atomicMin
    // (valid ordering since d2 >= 0 so all float bit patterns are positive).
#pragma unroll
    for (int k = 0; k < SRC_PER_THREAD; ++k) {
        float s2 = fmaf(sx[k], sx[k], fmaf(sy[k], sy[k], sz[k] * sz[k]));
        float d  = fmaxf(mn[k] + s2, 0.0f);
        atomicMin(&outmin[nbase + k * TPB], __float_as_uint(d));
    }
}

// ---------------------------------------------------------------------------
// Reduce: one block per (direction, batch). N == M == 4096, so
// mean_n(min) + mean_m(min) = (sum of both arrays) / 4096.
// ---------------------------------------------------------------------------
__global__ __launch_bounds__(TPB) void chamfer_reduce_kernel(
    const float* __restrict__ minbuf,   // [2][BQ][4096]
    const float* __restrict__ weights,  // [BQ]
    float* __restrict__ out) {
    const int idx = blockIdx.x;          // 0..31 = dir*BQ + b
    const int b = idx & (BQ - 1);
    const float* m0 = minbuf + (size_t)idx * NP;

    float s = 0.0f;
    for (int i = threadIdx.x; i < NP; i += TPB) s += m0[i];

    // wave64 reduce
#pragma unroll
    for (int off = 32; off > 0; off >>= 1) s += __shfl_down(s, off, 64);

    __shared__ float red[TPB / 64];
    if ((threadIdx.x & 63) == 0) red[threadIdx.x >> 6] = s;
    __syncthreads();
    if (threadIdx.x == 0) {
        float tot = 0.0f;
#pragma unroll
        for (int w = 0; w < TPB / 64; ++w) tot += red[w];
        atomicAdd(out, weights[b] * tot * (1.0f / ((float)NP * (float)BQ)));
    }
}

// ---------------------------------------------------------------------------
extern "C" void kernel_launch(void* const* d_in, const int* in_sizes, int n_in,
                              void* d_out, int out_size, void* d_ws, size_t ws_size,
                              hipStream_t stream) {
    const float* src = (const float*)d_in[0];
    const float* tgt = (const float*)d_in[1];
    const float* wts = (const float*)d_in[2];
    float* out = (float*)d_out;

    unsigned int* minbuf = (unsigned int*)d_ws;  // 2*BQ*NP floats = 512 KB
    const int minElems = 2 * BQ * NP;

    chamfer_init_kernel<<<(minElems + TPB - 1) / TPB, TPB, 0, stream>>>(
        minbuf, minElems, out);

    dim3 grid(NP / NCHUNK, MSPLIT, 2 * BQ);  // (2, 16, 32) = 1024 blocks
    chamfer_dir_kernel<<<grid, TPB, 0, stream>>>(src, tgt, minbuf);

    chamfer_reduce_kernel<<<2 * BQ, TPB, 0, stream>>>((const float*)minbuf, wts, out);
}

// Round 3
// 91.550 us; speedup vs baseline: 1.1637x; 1.1505x over previous
//
#include <hip/hip_runtime.h>

// Problem constants (reference shapes)
#define BQ 16
#define NP 4096
#define MP 4096

constexpr int TPB = 256;            // 4 waves
constexpr int CHUNK = 256;          // targets staged per LDS tile
constexpr int SRC_PER_BLOCK = 128;  // 4 waves x 32 source columns

typedef __bf16 bf16x8 __attribute__((ext_vector_type(8)));
typedef float f32x16 __attribute__((ext_vector_type(16)));

union Frag {
    unsigned short u[8];
    bf16x8 v;
    int4 i4;
};

// RNE float -> bf16 bits (no NaN inputs here)
__device__ inline unsigned short f2bf(float f) {
    unsigned u = __float_as_uint(f);
    return (unsigned short)((u + 0x7FFFu + ((u >> 16) & 1u)) >> 16);
}
__device__ inline float bf2f(unsigned short h) {
    return __uint_as_float(((unsigned)h) << 16);
}

__global__ void chamfer_zero_kernel(float* __restrict__ out) { out[0] = 0.0f; }

// ---------------------------------------------------------------------------
// MFMA chamfer kernel. grid = (NP/SRC_PER_BLOCK, 2*BQ) = (32, 32).
// d2(i,j) = K=13 bf16 dot product (hi/lo split): rows i = "targets" (A),
// cols j = "sources" (B). Each lane's 16 C-regs are 16 rows of one col, so
// the min over targets is an in-lane min-tree + one xor-32 shuffle.
// s2/t2 are folded into the dot; max(.,0) applied after the min (monotone).
// Block covers ALL targets for its 128 sources -> no cross-block min combine;
// block sums its per-source mins and does one weighted atomicAdd to out.
// ---------------------------------------------------------------------------
__global__ __launch_bounds__(TPB) void chamfer_mfma_kernel(
    const float* __restrict__ srcp,   // [BQ][NP][3]
    const float* __restrict__ tgtp,   // [BQ][MP][3]
    const float* __restrict__ wts,    // [BQ]
    float* __restrict__ out)          // scalar
{
    const int gy  = blockIdx.y;
    const int dir = gy >> 4;
    const int b   = gy & 15;
    // dir0: cols(B)=src points, rows(A)=tgt points; dir1: swapped.
    const float* S = dir ? (tgtp + (size_t)b * MP * 3) : (srcp + (size_t)b * NP * 3);
    const float* T = dir ? (srcp + (size_t)b * NP * 3) : (tgtp + (size_t)b * MP * 3);

    const int tid  = threadIdx.x;
    const int lane = tid & 63;
    const int half = lane >> 5;   // K-half for A/B operands
    const int col  = lane & 31;   // source column
    const int wave = tid >> 6;

    __shared__ unsigned short sh[CHUNK * 16];  // 8 KB expanded A tiles
    __shared__ float partial[TPB / 64];

    const unsigned short ONE = 0x3F80;  // bf16(1.0)

    // ---- B fragment (source side), fixed for the whole kernel ----
    Frag bfrag;
    {
        const int sidx = blockIdx.x * SRC_PER_BLOCK + wave * 32 + col;
        const float* sp = S + (size_t)sidx * 3;
        float x = sp[0], y = sp[1], z = sp[2];
        // split u = -2*coord into bf16 hi+lo
        unsigned short uh0 = f2bf(-2.0f * x), uh1 = f2bf(-2.0f * y), uh2 = f2bf(-2.0f * z);
        unsigned short ul0 = f2bf(-2.0f * x - bf2f(uh0));
        unsigned short ul1 = f2bf(-2.0f * y - bf2f(uh1));
        unsigned short ul2 = f2bf(-2.0f * z - bf2f(uh2));
        float s2 = fmaf(x, x, fmaf(y, y, z * z));
        unsigned short s2h = f2bf(s2), s2l = f2bf(s2 - bf2f(s2h));
        if (half == 0) {  // k = 0..7
            bfrag.u[0] = uh0; bfrag.u[1] = uh1; bfrag.u[2] = uh2;
            bfrag.u[3] = ul0; bfrag.u[4] = ul1; bfrag.u[5] = ul2;
            bfrag.u[6] = uh0; bfrag.u[7] = uh1;
        } else {          // k = 8..15
            bfrag.u[0] = uh2; bfrag.u[1] = ONE; bfrag.u[2] = ONE;
            bfrag.u[3] = s2h; bfrag.u[4] = s2l;
            bfrag.u[5] = 0;   bfrag.u[6] = 0;   bfrag.u[7] = 0;
        }
    }

    float accm = __int_as_float(0x7F800000);  // +inf running min per source col

    for (int c = 0; c < MP / CHUNK; ++c) {
        // ---- stage: each thread expands one target into two 16B K-planes ----
        {
            const float* tp = T + (size_t)(c * CHUNK + tid) * 3;
            float x = tp[0], y = tp[1], z = tp[2];
            unsigned short xh = f2bf(x), yh = f2bf(y), zh = f2bf(z);
            unsigned short xl = f2bf(x - bf2f(xh));
            unsigned short yl = f2bf(y - bf2f(yh));
            unsigned short zl = f2bf(z - bf2f(zh));
            float t2 = fmaf(x, x, fmaf(y, y, z * z));
            unsigned short t2h = f2bf(t2), t2l = f2bf(t2 - bf2f(t2h));
            Frag p0, p1;
            p0.u[0] = xh; p0.u[1] = yh; p0.u[2] = zh;   // k0..2: th
            p0.u[3] = xh; p0.u[4] = yh; p0.u[5] = zh;   // k3..5: th (pairs with sl)
            p0.u[6] = xl; p0.u[7] = yl;                 // k6..7: tl0, tl1
            p1.u[0] = zl;                               // k8: tl2
            p1.u[1] = t2h; p1.u[2] = t2l;               // k9..10
            p1.u[3] = ONE; p1.u[4] = ONE;               // k11..12
            p1.u[5] = 0; p1.u[6] = 0; p1.u[7] = 0;
            const int sub = tid >> 5, row = tid & 31;
            *(int4*)&sh[sub * 512 + row * 8]       = p0.i4;
            *(int4*)&sh[sub * 512 + 256 + row * 8] = p1.i4;
        }
        __syncthreads();

        // ---- compute: 8 sub-chunks of 32 targets ----
#pragma unroll
        for (int sc = 0; sc < CHUNK / 32; ++sc) {
            Frag a;
            a.i4 = *(const int4*)&sh[sc * 512 + half * 256 + col * 8];
            f32x16 zc = {};
            f32x16 d = __builtin_amdgcn_mfma_f32_32x32x16_bf16(a.v, bfrag.v, zc, 0, 0, 0);
            float m0 = fminf(fminf(d[0], d[1]), d[2]);
            float m1 = fminf(fminf(d[3], d[4]), d[5]);
            float m2 = fminf(fminf(d[6], d[7]), d[8]);
            float m3 = fminf(fminf(d[9], d[10]), d[11]);
            float m4 = fminf(fminf(d[12], d[13]), d[14]);
            float t0 = fminf(fminf(m0, m1), m2);
            float t1 = fminf(fminf(m3, m4), d[15]);
            accm = fminf(fminf(accm, t0), t1);
        }
        __syncthreads();
    }

    // ---- epilogue: combine row-halves, clamp, sum the wave's 32 sources ----
    float m = fminf(accm, __shfl_xor(accm, 32, 64));
    m = fmaxf(m, 0.0f);
#pragma unroll
    for (int off = 16; off > 0; off >>= 1) m += __shfl_xor(m, off, 64);
    if (lane == 0) partial[wave] = m;
    __syncthreads();
    if (tid == 0) {
        float v = partial[0] + partial[1] + partial[2] + partial[3];
        atomicAdd(out, v * wts[b] * (1.0f / ((float)NP * (float)BQ)));
    }
}

// ---------------------------------------------------------------------------
extern "C" void kernel_launch(void* const* d_in, const int* in_sizes, int n_in,
                              void* d_out, int out_size, void* d_ws, size_t ws_size,
                              hipStream_t stream) {
    const float* src = (const float*)d_in[0];
    const float* tgt = (const float*)d_in[1];
    const float* wts = (const float*)d_in[2];
    float* out = (float*)d_out;

    chamfer_zero_kernel<<<1, 1, 0, stream>>>(out);

    dim3 grid(NP / SRC_PER_BLOCK, 2 * BQ);  // (32, 32) = 1024 blocks
    chamfer_mfma_kernel<<<grid, TPB, 0, stream>>>(src, tgt, wts, out);
}